// Round 1
// baseline (1687.261 us; speedup 1.0000x reference)
//
#include <hip/hip_runtime.h>
#include <hip/hip_bf16.h>
#include <stdint.h>

#define M_DIM 8192
#define N_DIM 11008
#define K_DIM 4096

typedef __bf16 bf16x8 __attribute__((ext_vector_type(8)));
typedef float floatx4 __attribute__((ext_vector_type(4)));

__device__ __forceinline__ void async_copy16(const void* g, void* l) {
    __builtin_amdgcn_global_load_lds(
        (const __attribute__((address_space(1))) unsigned int*)g,
        (__attribute__((address_space(3))) unsigned int*)l,
        16, 0, 0);
}

// ---- prepass: x fp32 -> bf16 (8 elems/thread) ----
__global__ void cvt_x_kernel(const float* __restrict__ x, bf16x8* __restrict__ o) {
    int i = blockIdx.x * 256 + threadIdx.x;
    const float4* xv = (const float4*)x;
    float4 a = xv[2 * (size_t)i];
    float4 b = xv[2 * (size_t)i + 1];
    bf16x8 v;
    v[0] = (__bf16)a.x; v[1] = (__bf16)a.y; v[2] = (__bf16)a.z; v[3] = (__bf16)a.w;
    v[4] = (__bf16)b.x; v[5] = (__bf16)b.y; v[6] = (__bf16)b.z; v[7] = (__bf16)b.w;
    o[i] = v;
}

// ---- prepass: W fp32 -> bf16 with fused block-dequant scale ----
// W is (N_DIM, K_DIM) row-major; scale is (N/128, K/128) = (86, 32).
__global__ void cvt_w_kernel(const float* __restrict__ w, const float* __restrict__ s,
                             bf16x8* __restrict__ o) {
    int i = blockIdx.x * 256 + threadIdx.x;   // one thread = 8 consecutive k
    int n  = i >> 9;          // K_DIM/8 = 512 threads per row
    int k8 = i & 511;
    float sc = s[(n >> 7) * 32 + (k8 >> 4)];  // k = k8*8 ; k/128 = k8/16
    const float4* wv = (const float4*)w;
    float4 a = wv[2 * (size_t)i];
    float4 b = wv[2 * (size_t)i + 1];
    bf16x8 v;
    v[0] = (__bf16)(a.x * sc); v[1] = (__bf16)(a.y * sc);
    v[2] = (__bf16)(a.z * sc); v[3] = (__bf16)(a.w * sc);
    v[4] = (__bf16)(b.x * sc); v[5] = (__bf16)(b.y * sc);
    v[6] = (__bf16)(b.z * sc); v[7] = (__bf16)(b.w * sc);
    o[i] = v;
}

// ---- GEMM: C[m][n] = sum_k A[m][k] * B[n][k], A: MxK bf16, B: NxK bf16, C: MxN fp32
// m97 structure: 128x128 tile, 4 waves, each 64x64 via 4x4 of 16x16x32 MFMA, BK=32.
__global__ __launch_bounds__(256) void gemm_bt_kernel(const __bf16* __restrict__ A,
                                                      const __bf16* __restrict__ B,
                                                      float* __restrict__ C) {
    __shared__ __bf16 As[128 * 32];   // 8 KB, row-major, 32 bf16 (64 B) per row
    __shared__ __bf16 Bs[128 * 32];   // 8 KB

    const int t    = threadIdx.x;
    const int lane = t & 63;
    const int wave = t >> 6;
    const int quad = lane >> 4;
    const int r    = lane & 15;
    const int wm   = (wave & 1) * 64;
    const int wn   = (wave >> 1) * 64;
    const int tm   = blockIdx.y * 128;
    const int tn   = blockIdx.x * 128;

    floatx4 acc[4][4] = {};

    // staging: thread t loads 16 B; LDS layout contiguous (no padding — required
    // by global_load_lds wave-uniform-base + lane*16 semantics)
    const int arow  = t >> 2;          // 0..63 (row within half-tile)
    const int acolb = (t & 3) * 16;    // byte offset within the 64 B row
    const char* gA = (const char*)(A + (size_t)tm * K_DIM);
    const char* gB = (const char*)(B + (size_t)tn * K_DIM);
    char* lA = (char*)As + wave * 1024;   // wave-uniform LDS base
    char* lB = (char*)Bs + wave * 1024;

    const bf16x8* Av = (const bf16x8*)As;
    const bf16x8* Bv = (const bf16x8*)Bs;

    for (int k0 = 0; k0 < K_DIM; k0 += 32) {
        __syncthreads();   // prior iteration's LDS reads done
        {
            const char* ga0 = gA + ((size_t)arow * K_DIM + k0) * 2 + acolb;
            const char* ga1 = gA + ((size_t)(64 + arow) * K_DIM + k0) * 2 + acolb;
            async_copy16(ga0, lA);
            async_copy16(ga1, lA + 4096);
            const char* gb0 = gB + ((size_t)arow * K_DIM + k0) * 2 + acolb;
            const char* gb1 = gB + ((size_t)(64 + arow) * K_DIM + k0) * 2 + acolb;
            async_copy16(gb0, lB);
            async_copy16(gb1, lB + 4096);
        }
        __syncthreads();   // compiler emits s_waitcnt vmcnt(0) before s_barrier

        bf16x8 af[4], bfr[4];
#pragma unroll
        for (int mi = 0; mi < 4; ++mi)
            af[mi] = Av[(wm + mi * 16 + r) * 4 + quad];   // A[m=lane&15][k=quad*8+j]
#pragma unroll
        for (int ni = 0; ni < 4; ++ni)
            bfr[ni] = Bv[(wn + ni * 16 + r) * 4 + quad];  // B[n=lane&15][k=quad*8+j]

#pragma unroll
        for (int mi = 0; mi < 4; ++mi)
#pragma unroll
            for (int ni = 0; ni < 4; ++ni)
                acc[mi][ni] = __builtin_amdgcn_mfma_f32_16x16x32_bf16(
                    af[mi], bfr[ni], acc[mi][ni], 0, 0, 0);
    }

    // epilogue: C/D layout (m89/m91 verified): n = lane&15, m = quad*4 + reg
#pragma unroll
    for (int mi = 0; mi < 4; ++mi) {
#pragma unroll
        for (int rr = 0; rr < 4; ++rr) {
            int row = tm + wm + mi * 16 + quad * 4 + rr;
            float* cp = C + (size_t)row * N_DIM + tn + wn + r;
#pragma unroll
            for (int ni = 0; ni < 4; ++ni)
                cp[ni * 16] = acc[mi][ni][rr];
        }
    }
}

extern "C" void kernel_launch(void* const* d_in, const int* in_sizes, int n_in,
                              void* d_out, int out_size, void* d_ws, size_t ws_size,
                              hipStream_t stream) {
    const float* x = (const float*)d_in[0];           // (4,2048,4096) fp32
    const float* w = (const float*)d_in[1];           // (11008,4096) fp32
    const float* s = (const float*)d_in[2];           // (86,32) fp32
    float* out = (float*)d_out;                       // (4,2048,11008) fp32

    __bf16* xb = (__bf16*)d_ws;                                        // 67 MB
    __bf16* wb = (__bf16*)((char*)d_ws + (size_t)M_DIM * K_DIM * 2);   // 90 MB

    cvt_x_kernel<<<M_DIM * K_DIM / 8 / 256, 256, 0, stream>>>(x, (bf16x8*)xb);
    cvt_w_kernel<<<N_DIM * K_DIM / 8 / 256, 256, 0, stream>>>(w, s, (bf16x8*)wb);

    dim3 grid(N_DIM / 128, M_DIM / 128);   // 86 x 64 = 5504 blocks
    gemm_bt_kernel<<<grid, 256, 0, stream>>>(xb, wb, out);
}